// Round 1
// baseline (103.920 us; speedup 1.0000x reference)
//
#include <hip/hip_runtime.h>

#define N_SOURCE   100000
#define N_TARGET   4096
#define SOURCE_DIM 512
#define EMBED_DIM  32
#define TARGET_DIM 16

// ---------------------------------------------------------------------------
// Kernel 0: M = embed @ weight   [SOURCE_DIM][TARGET_DIM]
// grid 32 x 256 threads; one element per thread (32 FMA each). Negligible cost.
// ---------------------------------------------------------------------------
__global__ __launch_bounds__(256)
void k_embed_weight(const float* __restrict__ embed,   // [512][32]
                    const float* __restrict__ weight,  // [32][16]
                    float* __restrict__ M) {           // [512][16]
    __shared__ float wlds[EMBED_DIM * TARGET_DIM];     // 512 floats
    int tid = threadIdx.x;
    for (int i = tid; i < EMBED_DIM * TARGET_DIM; i += 256)
        wlds[i] = weight[i];
    __syncthreads();

    int idx = blockIdx.x * 256 + tid;                  // 0..8191
    if (idx < SOURCE_DIM * TARGET_DIM) {
        int k = idx >> 4;        // embed row
        int o = idx & 15;        // output col
        float s = 0.f;
        #pragma unroll
        for (int j = 0; j < EMBED_DIM; ++j)
            s += embed[k * EMBED_DIM + j] * wlds[j * TARGET_DIM + o];
        M[idx] = s;
    }
}

// ---------------------------------------------------------------------------
// Kernel 1: y[r][:] = (source_feat[r][:] @ M) / x_norm[r]     [N_SOURCE][16]
// Block: 256 threads, 64 rows per block. thread -> (row = tid&63, 4 cols).
// A tile staged in LDS with pad 68 (conflict-free b128 reads); M in LDS,
// read with wave-uniform (broadcast) addresses.
// ---------------------------------------------------------------------------
#define TM 64
#define KB 64
#define LDA_PAD 68

__global__ __launch_bounds__(256)
void k_gemm_y(const float* __restrict__ A,       // source_feat [N_SOURCE][512]
              const float* __restrict__ xnorm,   // [N_SOURCE]
              const float* __restrict__ M,       // [512][16]
              float* __restrict__ y) {           // [N_SOURCE][16]
    __shared__ float Mlds[SOURCE_DIM * TARGET_DIM];  // 32 KB
    __shared__ float Alds[TM * LDA_PAD];             // 17.4 KB

    int tid = threadIdx.x;
    int r0  = blockIdx.x * TM;

    // load M into LDS: 2048 float4s, 8 per thread, coalesced
    #pragma unroll
    for (int i = 0; i < 8; ++i) {
        int f = tid + 256 * i;
        *(float4*)&Mlds[f * 4] = *(const float4*)&M[f * 4];
    }

    float ax = 0.f, ay = 0.f, az = 0.f, aw = 0.f;
    int row = tid & 63;
    int c0  = (tid >> 6) * 4;    // wave-uniform -> Mlds reads broadcast

    for (int kc = 0; kc < SOURCE_DIM; kc += KB) {
        __syncthreads();   // also covers the initial M load
        // stage A[r0..r0+63][kc..kc+63]: 1024 float4s, 4 per thread, coalesced
        #pragma unroll
        for (int i = 0; i < 4; ++i) {
            int f  = tid + 256 * i;
            int ar = f >> 4;          // 0..63
            int cg = f & 15;          // 0..15
            float4 v = make_float4(0.f, 0.f, 0.f, 0.f);
            int gr = r0 + ar;
            if (gr < N_SOURCE)
                v = *(const float4*)&A[(size_t)gr * SOURCE_DIM + kc + cg * 4];
            *(float4*)&Alds[ar * LDA_PAD + cg * 4] = v;
        }
        __syncthreads();

        #pragma unroll
        for (int k = 0; k < KB; k += 4) {
            float4 a4 = *(float4*)&Alds[row * LDA_PAD + k];
            float4 m0 = *(float4*)&Mlds[(kc + k + 0) * TARGET_DIM + c0];
            float4 m1 = *(float4*)&Mlds[(kc + k + 1) * TARGET_DIM + c0];
            float4 m2 = *(float4*)&Mlds[(kc + k + 2) * TARGET_DIM + c0];
            float4 m3 = *(float4*)&Mlds[(kc + k + 3) * TARGET_DIM + c0];
            ax += a4.x * m0.x + a4.y * m1.x + a4.z * m2.x + a4.w * m3.x;
            ay += a4.x * m0.y + a4.y * m1.y + a4.z * m2.y + a4.w * m3.y;
            az += a4.x * m0.z + a4.y * m1.z + a4.z * m2.z + a4.w * m3.z;
            aw += a4.x * m0.w + a4.y * m1.w + a4.z * m2.w + a4.w * m3.w;
        }
    }

    int gr = r0 + row;
    if (gr < N_SOURCE) {
        float inv = 1.0f / xnorm[gr];
        float4 r  = make_float4(ax * inv, ay * inv, az * inv, aw * inv);
        *(float4*)&y[(size_t)gr * TARGET_DIM + c0] = r;
    }
}

// ---------------------------------------------------------------------------
// Kernel 2: out[t][:] = mean over edges of y[src[e]][:]
// one block (256 thr) per target; 64 edge slots x 4 lanes (float4 each);
// wave butterfly over slot bits, then tiny LDS cross-wave reduce.
// ---------------------------------------------------------------------------
__global__ __launch_bounds__(256)
void k_gather_mean(const float* __restrict__ y,    // [N_SOURCE][16]
                   const int*   __restrict__ src,  // edge_index row 0
                   const int*   __restrict__ rl,   // range_list [N_TARGET][2]
                   float* __restrict__ out) {      // [N_TARGET][16]
    int t     = blockIdx.x;
    int tid   = threadIdx.x;
    int start = rl[2 * t];
    int end   = rl[2 * t + 1];

    int slot = tid >> 2;   // 0..63
    int sub  = tid & 3;    // which float4 of the 16-float row

    float ax = 0.f, ay = 0.f, az = 0.f, aw = 0.f;
    for (int e = start + slot; e < end; e += 64) {
        int s = src[e];
        float4 v = *(const float4*)&y[(size_t)s * TARGET_DIM + sub * 4];
        ax += v.x; ay += v.y; az += v.z; aw += v.w;
    }

    // butterfly over slot bits within the wave (lane bits 2..5)
    #pragma unroll
    for (int m = 4; m <= 32; m <<= 1) {
        ax += __shfl_xor(ax, m);
        ay += __shfl_xor(ay, m);
        az += __shfl_xor(az, m);
        aw += __shfl_xor(aw, m);
    }

    __shared__ float red[4][16];
    int wid  = tid >> 6;
    int lane = tid & 63;
    if (lane < 4) {
        red[wid][lane * 4 + 0] = ax;
        red[wid][lane * 4 + 1] = ay;
        red[wid][lane * 4 + 2] = az;
        red[wid][lane * 4 + 3] = aw;
    }
    __syncthreads();

    if (tid < TARGET_DIM) {
        float s = red[0][tid] + red[1][tid] + red[2][tid] + red[3][tid];
        float deg = (float)(end - start);
        deg = deg > 1.f ? deg : 1.f;
        out[t * TARGET_DIM + tid] = s / deg;
    }
}

// ---------------------------------------------------------------------------
extern "C" void kernel_launch(void* const* d_in, const int* in_sizes, int n_in,
                              void* d_out, int out_size, void* d_ws, size_t ws_size,
                              hipStream_t stream) {
    const float* source_feat = (const float*)d_in[0];  // [100000][512]
    const float* embed       = (const float*)d_in[1];  // [512][32]
    const float* weight      = (const float*)d_in[2];  // [32][16]
    const int*   edge_src    = (const int*)d_in[3];    // edge_index[0][:] (row 0)
    const int*   range_list  = (const int*)d_in[4];    // [4096][2]
    const float* x_norm      = (const float*)d_in[5];  // [100000]

    float* out = (float*)d_out;
    float* M   = (float*)d_ws;                          // 32 KB
    float* y   = (float*)((char*)d_ws + 32768);         // 6.4 MB

    k_embed_weight<<<32, 256, 0, stream>>>(embed, weight, M);

    int nblk = (N_SOURCE + TM - 1) / TM;               // 1563
    k_gemm_y<<<nblk, 256, 0, stream>>>(source_feat, x_norm, M, y);

    k_gather_mean<<<N_TARGET, 256, 0, stream>>>(y, edge_src, range_list, out);
}